// Round 7
// baseline (93.439 us; speedup 1.0000x reference)
//
#include <hip/hip_runtime.h>
#include <hip/hip_bf16.h>

#define LOG2E 1.4426950408889634f
#define SC2   2.8853900817779268f   // 2*log2(e)

typedef __attribute__((ext_vector_type(8))) short short8b;   // 8 bf16 (4 VGPR)
typedef __attribute__((ext_vector_type(4))) short short4b;   // 4 bf16 (8 B)
typedef __attribute__((ext_vector_type(4))) float f32x4;

__device__ __forceinline__ float fast_exp2(float x) {
#if __has_builtin(__builtin_amdgcn_exp2f)
  return __builtin_amdgcn_exp2f(x);
#else
  return exp2f(x);
#endif
}
__device__ __forceinline__ float fast_rcp(float x) {
#if __has_builtin(__builtin_amdgcn_rcpf)
  return __builtin_amdgcn_rcpf(x);
#else
  return 1.0f / x;
#endif
}
__device__ __forceinline__ short f2bf(float f) {
  __hip_bfloat16 h = __float2bfloat16(f);
  return *reinterpret_cast<short*>(&h);
}

// ---------------------------------------------------------------------------
// Stage 1: O = relu(X @ W^T + bias) via bf16 MFMA (f32 accumulate).
// Tile 128x64, 4 waves (2x2), per-wave 64x32 = 4x2 frags of 16x16.
// ---------------------------------------------------------------------------
__global__ __launch_bounds__(256) void gemm_mfma_kernel(
    const float* __restrict__ Xa, const float* __restrict__ Wa,
    const float* __restrict__ ba, float* __restrict__ Oa,
    const float* __restrict__ Xb, const float* __restrict__ Wb,
    const float* __restrict__ bb, float* __restrict__ Ob) {
  const float* X = blockIdx.z ? Xb : Xa;
  const float* W = blockIdx.z ? Wb : Wa;
  const float* bias = blockIdx.z ? bb : ba;
  float* O = blockIdx.z ? Ob : Oa;

  __shared__ __align__(16) short As[128 * 40];  // 128 rows x 32 bf16 (+8 pad)
  __shared__ __align__(16) short Ws[64 * 40];

  int t = threadIdx.x;
  int m0 = blockIdx.x * 128, n0 = blockIdx.y * 64;
  int l = t & 63, w = t >> 6;
  int wm = (w >> 1) * 64, wn = (w & 1) * 32;
  int lr = l & 15, ko = (l >> 4) * 8;

  f32x4 acc[4][2];
#pragma unroll
  for (int m = 0; m < 4; ++m)
#pragma unroll
    for (int n = 0; n < 2; ++n) acc[m][n] = f32x4{0.f, 0.f, 0.f, 0.f};

  for (int k0 = 0; k0 < 512; k0 += 32) {
#pragma unroll
    for (int s = 0; s < 4; ++s) {
      int slot = t + s * 256;
      int row = slot >> 3, q = (slot & 7) << 2;
      float4 v = *reinterpret_cast<const float4*>(&X[(m0 + row) * 512 + k0 + q]);
      short4b sv = {f2bf(v.x), f2bf(v.y), f2bf(v.z), f2bf(v.w)};
      *reinterpret_cast<short4b*>(&As[row * 40 + q]) = sv;
    }
#pragma unroll
    for (int s = 0; s < 2; ++s) {
      int slot = t + s * 256;
      int row = slot >> 3, q = (slot & 7) << 2;
      float4 v = *reinterpret_cast<const float4*>(&W[(n0 + row) * 512 + k0 + q]);
      short4b sv = {f2bf(v.x), f2bf(v.y), f2bf(v.z), f2bf(v.w)};
      *reinterpret_cast<short4b*>(&Ws[row * 40 + q]) = sv;
    }
    __syncthreads();

    short8b afr[4], bfr[2];
#pragma unroll
    for (int m = 0; m < 4; ++m)
      afr[m] = *reinterpret_cast<const short8b*>(&As[(wm + m * 16 + lr) * 40 + ko]);
#pragma unroll
    for (int n = 0; n < 2; ++n)
      bfr[n] = *reinterpret_cast<const short8b*>(&Ws[(wn + n * 16 + lr) * 40 + ko]);
#pragma unroll
    for (int m = 0; m < 4; ++m)
#pragma unroll
      for (int n = 0; n < 2; ++n)
        acc[m][n] = __builtin_amdgcn_mfma_f32_16x16x32_bf16(afr[m], bfr[n], acc[m][n], 0, 0, 0);
    __syncthreads();
  }

#pragma unroll
  for (int n = 0; n < 2; ++n) {
    int col = n0 + wn + n * 16 + lr;
    float bv = bias[col];
#pragma unroll
    for (int m = 0; m < 4; ++m) {
      int rbase = m0 + wm + m * 16 + (l >> 4) * 4;
#pragma unroll
      for (int r = 0; r < 4; ++r) {
        float v = acc[m][n][r] + bv;
        O[(rbase + r) * 512 + col] = v > 0.f ? v : 0.f;
      }
    }
  }
}

// ---------------------------------------------------------------------------
// Stage 1.5: per bh (one block), SORT the 256 j's by nnz (descending bitonic),
// then pack nonzero B entries of rank-consecutive groups of 8 j's into an
// interleaved layout entry[s][jj], zero-padded to the group max (even).
// Pair = (B*2log2e, qm), qm = -2*q[c] with low 8 mantissa bits = c<<2
// (byte offset; rel perturb 3e-5).  Jmap[rank]=jorig for colsum scatter;
// Ksum[jorig] = sum_{nz} q_c (column-softmax shift, unpermuted).
// ---------------------------------------------------------------------------
__global__ __launch_bounds__(256) void compact_kernel(
    const float* __restrict__ Br, const float* __restrict__ q,
    float2* __restrict__ Cb, unsigned* __restrict__ Cnt,
    float* __restrict__ Ksum, unsigned* __restrict__ Jmap) {
  int bh = blockIdx.x;
  int t = threadIdx.x;
  __shared__ int keys[256];
  __shared__ float qls[64];
  if (t < 64) qls[t] = q[t];
  __syncthreads();

  const float* Brow = Br + bh * 16384 + t * 64;
  int nnz = 0;
  float K = 0.f;
#pragma unroll
  for (int c4 = 0; c4 < 64; c4 += 4) {
    float4 v = *reinterpret_cast<const float4*>(&Brow[c4]);
    if (v.x > 0.f) { ++nnz; K += qls[c4 + 0]; }
    if (v.y > 0.f) { ++nnz; K += qls[c4 + 1]; }
    if (v.z > 0.f) { ++nnz; K += qls[c4 + 2]; }
    if (v.w > 0.f) { ++nnz; K += qls[c4 + 3]; }
  }
  Ksum[bh * 256 + t] = K;        // indexed by original j == t
  keys[t] = (nnz << 8) | t;

  // bitonic sort, descending by nnz
  for (int k = 2; k <= 256; k <<= 1) {
    for (int s = k >> 1; s > 0; s >>= 1) {
      __syncthreads();
      int p = t ^ s;
      if (p > t) {
        int a = keys[t], b = keys[p];
        bool up = ((t & k) == 0);
        if (up ? (a < b) : (a > b)) { keys[t] = b; keys[p] = a; }
      }
    }
  }
  __syncthreads();

  int key = keys[t];
  int jorig = key & 255;
  int myn = key >> 8;
  int jg = t >> 3, jj = t & 7;
  int maxc = (keys[jg << 3] >> 8);     // descending -> first of group is max
  maxc = (maxc + 1) & ~1;              // even
  Jmap[bh * 256 + t] = (unsigned)jorig;
  if (jj == 0) Cnt[bh * 32 + jg] = (unsigned)maxc;

  const float* Bsrc = Br + bh * 16384 + jorig * 64;
  float2* dst = Cb + (size_t)(bh * 32 + jg) * 512 + jj;
  int kk = 0;
#pragma unroll 4
  for (int c = 0; c < 64; ++c) {
    float v = Bsrc[c];
    if (v > 0.f) {
      unsigned qb = (__float_as_uint(-2.f * qls[c]) & ~255u) | (unsigned)(c << 2);
      dst[kk * 8] = make_float2(v * SC2, __uint_as_float(qb));
      ++kk;
    }
  }
  for (; kk < maxc; ++kk) dst[kk * 8] = make_float2(0.f, 0.f);
  (void)myn;
}

// ---------------------------------------------------------------------------
// Stage 2 (sparse, sorted, interleaved): wave w owns group jg = gblk*4+w
// (rank-consecutive -> balanced); 64 lanes = 64 i-rows of a 64-row A-tile.
// ssplit halves each list so grid = 2x residency (tail backfill).
// Per iter: 2 s-steps x 8 jj = 16 evals, rcp-paired across s within jj.
// Pair data wave-uniform -> scalar loads.  A staged [i][c] pad-65.
// grid (8 gblk, 4 isplit x 2 ssplit, 64 bh), 256 threads.
// ---------------------------------------------------------------------------
#define PAIR(b0, q0, b1, q1, ACCJ) {                                        \
    float a0 = *(const float*)(AlsB + (__float_as_uint(q0) & 255u));        \
    float a1 = *(const float*)(AlsB + (__float_as_uint(q1) & 255u));        \
    float e0 = fast_exp2(a0 * (b0));                                        \
    float e1 = fast_exp2(a1 * (b1));                                        \
    float u0 = e0 + 1.f, u1 = e1 + 1.f;                                     \
    float nn = fmaf((q0), u1, (q1) * u0);                                   \
    ACCJ = fmaf(nn, fast_rcp(u0 * u1), ACCJ); }

__global__ __launch_bounds__(256, 8) void attmap_kernel(
    const float* __restrict__ Ar, const float2* __restrict__ Cb,
    const unsigned* __restrict__ Cnt, const unsigned* __restrict__ Jmap,
    float* __restrict__ rowpart, float* __restrict__ colsum) {
  int gblk = blockIdx.x;
  int isplit = blockIdx.y >> 1, ssplit = blockIdx.y & 1;
  int bh = blockIdx.z;
  int t = threadIdx.x;
  int il = t & 63;
  int w = __builtin_amdgcn_readfirstlane(t >> 6);   // wave id 0..3 (uniform)
  int jg = gblk * 4 + w;

  __shared__ __align__(16) float Als[64 * 65];
  __shared__ float red[256];
  __shared__ float cpart[4][8];

  const float* Abase = Ar + bh * 16384 + isplit * 4096;
#pragma unroll
  for (int it = 0; it < 4; ++it) {
    int idx = it * 256 + t;           // 1024 float4: 64 rows x 16 quads
    int r = idx >> 4, c4 = (idx & 15) << 2;
    float4 v = *reinterpret_cast<const float4*>(&Abase[r * 64 + c4]);
    Als[r * 65 + c4 + 0] = v.x; Als[r * 65 + c4 + 1] = v.y;
    Als[r * 65 + c4 + 2] = v.z; Als[r * 65 + c4 + 3] = v.w;
  }
  __syncthreads();

  const char* AlsB = (const char*)Als + il * 260;   // row base (65 f stride)
  float acc[8];
#pragma unroll
  for (int jj = 0; jj < 8; ++jj) acc[jj] = 0.f;

  int gi = bh * 32 + jg;
  int n = (int)__builtin_amdgcn_readfirstlane(Cnt[gi]);   // even
  int nh = ((n >> 1) + 1) & ~1;                           // even half (ceil)
  int s0 = ssplit ? nh : 0;
  int s1 = ssplit ? n : (nh < n ? nh : n);
  const float4* P4 = reinterpret_cast<const float4*>(Cb + (size_t)gi * 512);

#pragma unroll 1
  for (int s = s0; s < s1; s += 2) {
    const float4* S0 = P4 + s * 4;   // wave-uniform -> s_load
    float4 x0 = S0[0], x1 = S0[1], x2 = S0[2], x3 = S0[3];  // step s
    float4 y0 = S0[4], y1 = S0[5], y2 = S0[6], y3 = S0[7];  // step s+1
    PAIR(x0.x, x0.y, y0.x, y0.y, acc[0]);
    PAIR(x0.z, x0.w, y0.z, y0.w, acc[1]);
    PAIR(x1.x, x1.y, y1.x, y1.y, acc[2]);
    PAIR(x1.z, x1.w, y1.z, y1.w, acc[3]);
    PAIR(x2.x, x2.y, y2.x, y2.y, acc[4]);
    PAIR(x2.z, x2.w, y2.z, y2.w, acc[5]);
    PAIR(x3.x, x3.y, y3.x, y3.y, acc[6]);
    PAIR(x3.z, x3.w, y3.z, y3.w, acc[7]);
  }

  float rs = 0.f;
#pragma unroll
  for (int jj = 0; jj < 8; ++jj) rs += acc[jj];
  red[t] = rs;

  int lane = t & 63;
#pragma unroll
  for (int jj = 0; jj < 8; ++jj) {
    float v = acc[jj];
#pragma unroll
    for (int off = 32; off >= 1; off >>= 1) v += __shfl_xor(v, off);
    if (lane == 0) cpart[w][jj] = v;
  }
  __syncthreads();

  if (t < 64) {
    rowpart[((bh * 8 + gblk) * 2 + ssplit) * 256 + isplit * 64 + t] =
        red[t] + red[t + 64] + red[t + 128] + red[t + 192];
  } else if (t < 96) {
    int r = t - 64;                  // 0..31
    int ww = r >> 3, jj = r & 7;
    int rank = (gblk * 4 + ww) * 8 + jj;
    unsigned jorig = Jmap[bh * 256 + rank];
    colsum[((bh * 4 + isplit) * 2 + ssplit) * 256 + jorig] = cpart[ww][jj];
  }
}

// ---------------------------------------------------------------------------
// Stage 3: per (bh): softmax over 256 row/col means (+Kj shift on cols),
// temps to ws, pooled outputs into out[0:8192].  512 threads.
// ---------------------------------------------------------------------------
__global__ __launch_bounds__(512) void softmax_pool_kernel(
    const float* __restrict__ rowpart, const float* __restrict__ colsum,
    const float* __restrict__ Ksum,
    const float* __restrict__ A0, const float* __restrict__ B0,
    float* __restrict__ b2a, float* __restrict__ a2b, float* __restrict__ out) {
  int bh = blockIdx.x;
  int b = bh >> 3, h = bh & 7;
  int t = threadIdx.x;
  int tt = t & 255;
  int lane = t & 63, w = (t >> 6) & 3;
  __shared__ float redA[4], redB[4], redC[4], redD[4];
  __shared__ float tA[256], tB[256];
  __shared__ float pp[8][64];

  float r = 0.f;
#pragma unroll
  for (int p = 0; p < 16; ++p)
    r += rowpart[((bh * 8) * 2 + p) * 256 + tt];
  r *= (1.f / 256.f);
  float csum = 0.f;
#pragma unroll
  for (int p = 0; p < 8; ++p)
    csum += colsum[((bh * 4) * 2 + p) * 256 + tt];
  float cs = Ksum[bh * 256 + tt] + csum * (1.f / 256.f);

  float mr = r, mc = cs;
#pragma unroll
  for (int off = 32; off >= 1; off >>= 1) {
    mr = fmaxf(mr, __shfl_xor(mr, off));
    mc = fmaxf(mc, __shfl_xor(mc, off));
  }
  if (lane == 0) { redA[w] = mr; redB[w] = mc; }
  __syncthreads();
  mr = fmaxf(fmaxf(redA[0], redA[1]), fmaxf(redA[2], redA[3]));
  mc = fmaxf(fmaxf(redB[0], redB[1]), fmaxf(redB[2], redB[3]));

  float er = fast_exp2((r - mr) * LOG2E);
  float ec = fast_exp2((cs - mc) * LOG2E);
  float sr = er, sc = ec;
#pragma unroll
  for (int off = 32; off >= 1; off >>= 1) {
    sr += __shfl_xor(sr, off);
    sc += __shfl_xor(sc, off);
  }
  if (lane == 0) { redC[w] = sr; redD[w] = sc; }
  __syncthreads();
  sr = redC[0] + redC[1] + redC[2] + redC[3];
  sc = redD[0] + redD[1] + redD[2] + redD[3];

  float vb2a = er * fast_rcp(sr);
  float va2b = ec * fast_rcp(sc);
  tA[tt] = vb2a; tB[tt] = va2b;
  b2a[bh * 256 + tt] = vb2a;
  a2b[bh * 256 + tt] = va2b;
  __syncthreads();

  int c = t & 63, iq = t >> 6;  // 8 groups x 32 i
  const float* Ab = A0 + b * 131072 + h * 16384;
  const float* Bb = B0 + b * 131072 + h * 16384;
  float pa = 0.f, pb = 0.f;
#pragma unroll 4
  for (int ii = 0; ii < 32; ++ii) {
    int i = (iq << 5) + ii;
    pa = fmaf(Ab[i * 64 + c], tA[i], pa);
    pb = fmaf(Bb[i * 64 + c], tB[i], pb);
  }
  pp[iq][c] = pa;
  __syncthreads();
  if (t < 64) {
    float s = 0.f;
#pragma unroll
    for (int k = 0; k < 8; ++k) s += pp[k][t];
    out[b * 1024 + h * 64 + t] = s;
  }
  __syncthreads();
  pp[iq][c] = pb;
  __syncthreads();
  if (t < 64) {
    float s = 0.f;
#pragma unroll
    for (int k = 0; k < 8; ++k) s += pp[k][t];
    out[b * 1024 + 512 + h * 64 + t] = s;
  }
}

// ---------------------------------------------------------------------------
// Stage 4: out1[b,i] = mean_h temp_b2a ; out2[b,j] = mean_h temp_a2b
// ---------------------------------------------------------------------------
__global__ __launch_bounds__(256) void mean_heads_kernel(
    const float* __restrict__ b2a, const float* __restrict__ a2b,
    float* __restrict__ out) {
  int b = blockIdx.x, t = threadIdx.x;
  float s1 = 0.f, s2 = 0.f;
#pragma unroll
  for (int h = 0; h < 8; ++h) {
    s1 += b2a[(b * 8 + h) * 256 + t];
    s2 += a2b[(b * 8 + h) * 256 + t];
  }
  out[8192 + b * 256 + t] = s1 * 0.125f;
  out[10240 + b * 256 + t] = s2 * 0.125f;
}

extern "C" void kernel_launch(void* const* d_in, const int* in_sizes, int n_in,
                              void* d_out, int out_size, void* d_ws, size_t ws_size,
                              hipStream_t stream) {
  const float* A  = (const float*)d_in[0];
  const float* B  = (const float*)d_in[1];
  const float* W1 = (const float*)d_in[2];
  const float* b1 = (const float*)d_in[3];
  const float* W2 = (const float*)d_in[4];
  const float* b2 = (const float*)d_in[5];
  const float* q  = (const float*)d_in[6];
  float* out = (float*)d_out;
  float* ws = (float*)d_ws;

  float*    Ar      = ws;                          // 1,048,576 f
  float*    Brr     = ws + 1048576;                // 1,048,576 f (dead after compact)
  float*    rowpart = ws + 1048576;                // alias Brr: 64*8*2*256 = 262,144 f
  float*    colsum  = ws + 1048576 + 262144;       // 64*4*2*256 = 131,072 f
  float2*   Cb      = (float2*)(ws + 2097152);     // 2048 groups * 512 f2 (8 MB)
  unsigned* Cnt     = (unsigned*)(ws + 4194304);   // 2,048 u32
  unsigned* Jmap    = (unsigned*)(ws + 4196352);   // 16,384 u32
  float*    Ksum    = ws + 4212736;                // 16,384 f   (end ~16.9 MB)
  float*    b2a     = ws;                          // alias Ar (dead after attmap)
  float*    a2b     = ws + 16384;

  gemm_mfma_kernel<<<dim3(16, 8, 2), 256, 0, stream>>>(A, W1, b1, Ar, B, W2, b2, Brr);
  compact_kernel<<<64, 256, 0, stream>>>(Brr, q, Cb, Cnt, Ksum, Jmap);
  attmap_kernel<<<dim3(8, 8, 64), 256, 0, stream>>>(Ar, Cb, Cnt, Jmap, rowpart, colsum);
  softmax_pool_kernel<<<64, 512, 0, stream>>>(rowpart, colsum, Ksum, A, B, b2a, a2b, out);
  mean_heads_kernel<<<8, 256, 0, stream>>>(b2a, a2b, out);
}

// Round 8
// 82.394 us; speedup vs baseline: 1.1340x; 1.1340x over previous
//
#include <hip/hip_runtime.h>
#include <hip/hip_bf16.h>

#define LOG2E 1.4426950408889634f

typedef __attribute__((ext_vector_type(8))) short short8b;   // 8 bf16 (4 VGPR)
typedef __attribute__((ext_vector_type(4))) short short4b;   // 4 bf16 (8 B)
typedef __attribute__((ext_vector_type(4))) float f32x4;

__device__ __forceinline__ float fast_exp2(float x) {
#if __has_builtin(__builtin_amdgcn_exp2f)
  return __builtin_amdgcn_exp2f(x);
#else
  return exp2f(x);
#endif
}
__device__ __forceinline__ float fast_rcp(float x) {
#if __has_builtin(__builtin_amdgcn_rcpf)
  return __builtin_amdgcn_rcpf(x);
#else
  return 1.0f / x;
#endif
}
__device__ __forceinline__ short f2bf(float f) {
  __hip_bfloat16 h = __float2bfloat16(f);
  return *reinterpret_cast<short*>(&h);
}

// ---------------------------------------------------------------------------
// Stage 1: O = relu(X @ W^T + bias) via bf16 MFMA (f32 accumulate).
// Tile 128x64, 4 waves (2x2), per-wave 64x32 = 4x2 frags of 16x16.
// ---------------------------------------------------------------------------
__global__ __launch_bounds__(256) void gemm_mfma_kernel(
    const float* __restrict__ Xa, const float* __restrict__ Wa,
    const float* __restrict__ ba, float* __restrict__ Oa,
    const float* __restrict__ Xb, const float* __restrict__ Wb,
    const float* __restrict__ bb, float* __restrict__ Ob) {
  const float* X = blockIdx.z ? Xb : Xa;
  const float* W = blockIdx.z ? Wb : Wa;
  const float* bias = blockIdx.z ? bb : ba;
  float* O = blockIdx.z ? Ob : Oa;

  __shared__ __align__(16) short As[128 * 40];  // 128 rows x 32 bf16 (+8 pad)
  __shared__ __align__(16) short Ws[64 * 40];

  int t = threadIdx.x;
  int m0 = blockIdx.x * 128, n0 = blockIdx.y * 64;
  int l = t & 63, w = t >> 6;
  int wm = (w >> 1) * 64, wn = (w & 1) * 32;
  int lr = l & 15, ko = (l >> 4) * 8;

  f32x4 acc[4][2];
#pragma unroll
  for (int m = 0; m < 4; ++m)
#pragma unroll
    for (int n = 0; n < 2; ++n) acc[m][n] = f32x4{0.f, 0.f, 0.f, 0.f};

  for (int k0 = 0; k0 < 512; k0 += 32) {
#pragma unroll
    for (int s = 0; s < 4; ++s) {
      int slot = t + s * 256;
      int row = slot >> 3, q = (slot & 7) << 2;
      float4 v = *reinterpret_cast<const float4*>(&X[(m0 + row) * 512 + k0 + q]);
      short4b sv = {f2bf(v.x), f2bf(v.y), f2bf(v.z), f2bf(v.w)};
      *reinterpret_cast<short4b*>(&As[row * 40 + q]) = sv;
    }
#pragma unroll
    for (int s = 0; s < 2; ++s) {
      int slot = t + s * 256;
      int row = slot >> 3, q = (slot & 7) << 2;
      float4 v = *reinterpret_cast<const float4*>(&W[(n0 + row) * 512 + k0 + q]);
      short4b sv = {f2bf(v.x), f2bf(v.y), f2bf(v.z), f2bf(v.w)};
      *reinterpret_cast<short4b*>(&Ws[row * 40 + q]) = sv;
    }
    __syncthreads();

    short8b afr[4], bfr[2];
#pragma unroll
    for (int m = 0; m < 4; ++m)
      afr[m] = *reinterpret_cast<const short8b*>(&As[(wm + m * 16 + lr) * 40 + ko]);
#pragma unroll
    for (int n = 0; n < 2; ++n)
      bfr[n] = *reinterpret_cast<const short8b*>(&Ws[(wn + n * 16 + lr) * 40 + ko]);
#pragma unroll
    for (int m = 0; m < 4; ++m)
#pragma unroll
      for (int n = 0; n < 2; ++n)
        acc[m][n] = __builtin_amdgcn_mfma_f32_16x16x32_bf16(afr[m], bfr[n], acc[m][n], 0, 0, 0);
    __syncthreads();
  }

#pragma unroll
  for (int n = 0; n < 2; ++n) {
    int col = n0 + wn + n * 16 + lr;
    float bv = bias[col];
#pragma unroll
    for (int m = 0; m < 4; ++m) {
      int rbase = m0 + wm + m * 16 + (l >> 4) * 4;
#pragma unroll
      for (int r = 0; r < 4; ++r) {
        float v = acc[m][n][r] + bv;
        O[(rbase + r) * 512 + col] = v > 0.f ? v : 0.f;
      }
    }
  }
}

// ---------------------------------------------------------------------------
// Stage 1.5: per (bh, j) compact the nonzero B entries.
// Pair = (B*1024, qm): 1024 = LUT index scale (4096-entry table over [0,4]);
// qm = q[c] with the low 8 mantissa bits replaced by c<<2 (byte offset into
// the A row; rel perturb 3e-5 — harmless).  Lists padded to x4 with
// exact-zero pairs (b=0 -> idx 0 -> tanh 0, q=0 -> contributes exactly 0).
// grid 512 blocks; 256 threads = 32 j x 8 scanners; width-8 shfl prefix.
// ---------------------------------------------------------------------------
__global__ __launch_bounds__(256) void compact_kernel(
    const float* __restrict__ Br, const float* __restrict__ q,
    float2* __restrict__ Cb, unsigned* __restrict__ Cnt) {
  int blk = blockIdx.x;
  int bh = blk >> 3, jblk = blk & 7;
  int t = threadIdx.x;
  int jl = t >> 3, p = t & 7;
  __shared__ float Bls[32][65];
  __shared__ float qls[64];

  const float* Bbase = Br + bh * 16384 + jblk * 2048;
#pragma unroll
  for (int it = 0; it < 2; ++it) {
    int idx = it * 256 + t;           // 512 float4 slots: 32 rows x 16 quads
    int row = idx >> 4, c4 = (idx & 15) << 2;
    float4 v = *reinterpret_cast<const float4*>(&Bbase[row * 64 + c4]);
    Bls[row][c4 + 0] = v.x; Bls[row][c4 + 1] = v.y;
    Bls[row][c4 + 2] = v.z; Bls[row][c4 + 3] = v.w;
  }
  if (t < 64) qls[t] = q[t];
  __syncthreads();

  int c0 = p * 8;
  // pass 1: count
  int nz = 0;
#pragma unroll
  for (int cc = 0; cc < 8; ++cc) {
    if (Bls[jl][c0 + cc] > 0.f) ++nz;
  }
  // width-8 inclusive prefix over scanners
  int incl = nz;
#pragma unroll
  for (int d = 1; d < 8; d <<= 1) {
    int u = __shfl_up(incl, d, 8);
    if (p >= d) incl += u;
  }
  int off = incl - nz;
  int total = __shfl(incl, 7, 8);

  // pass 2: write
  float2* dst = Cb + (bh * 256 + jblk * 32 + jl) * 64;
  int k = off;
#pragma unroll
  for (int cc = 0; cc < 8; ++cc) {
    int c = c0 + cc;
    float v = Bls[jl][c];
    if (v > 0.f) {
      unsigned qb = (__float_as_uint(qls[c]) & ~255u) | (unsigned)(c << 2);
      dst[k] = make_float2(v * 1024.0f, __uint_as_float(qb));
      ++k;
    }
  }
  if (p == 7) {
    int cnt = total;
    while (cnt & 3) { dst[cnt] = make_float2(0.f, 0.f); ++cnt; }
    Cnt[bh * 256 + jblk * 32 + jl] = (unsigned)cnt;
  }
}

// ---------------------------------------------------------------------------
// Stage 2 (sparse, LUT tanh): M[i,j] = sum_{s in nz(j)} q_s * tanh(A_ic B_jc)
// tanh via 4096-entry f32 LDS table over [0,4] (nearest; a,b >= 0 so arg >= 0;
// index scale 1024 prefolded into b, +0.5 gives round-to-nearest, clamp 4095).
// Eval = fma, min, cvt, ds_read, fma — zero transcendental ops.
// Pair list wave-uniform -> scalar loads.  A staged [i][c] pad-65.
// grid (64 bh, 8 jblk, 2 isplit); 512 threads; g=t>>7 owns 8 j's, il=t&127.
// ---------------------------------------------------------------------------
__global__ __launch_bounds__(512, 6) void attmap_kernel(
    const float* __restrict__ Ar, const float2* __restrict__ Cb,
    const unsigned* __restrict__ Cnt,
    float* __restrict__ rowpart, float* __restrict__ colsum) {
  int bh = blockIdx.x, jblk = blockIdx.y, isplit = blockIdx.z;
  int t = threadIdx.x;
  int il = t & 127;
  int g = __builtin_amdgcn_readfirstlane(t >> 7);  // wave-uniform group id
  __shared__ __align__(16) float Als[128 * 65];    // 33280 B
  __shared__ __align__(16) float Tls[4096];        // 16384 B tanh table
  __shared__ float red[512];
  __shared__ float cpart[8][8];

  const float* Abase = Ar + bh * 16384 + isplit * 8192;
#pragma unroll
  for (int it = 0; it < 4; ++it) {
    int idx = it * 512 + t;           // float4 slot: 128 i x 16 quads
    int r = idx >> 4, c4 = (idx & 15) << 2;
    float4 v = *reinterpret_cast<const float4*>(&Abase[r * 64 + c4]);
    Als[r * 65 + c4 + 0] = v.x; Als[r * 65 + c4 + 1] = v.y;
    Als[r * 65 + c4 + 2] = v.z; Als[r * 65 + c4 + 3] = v.w;
  }
#pragma unroll
  for (int e = 0; e < 8; ++e) {
    int k = e * 512 + t;
    Tls[k] = tanhf((float)k * (1.0f / 1024.0f));
  }
  __syncthreads();

  const char* AlsB = (const char*)(&Als[il * 65]);

#define EV(BV, QV, ACCJ) {                                                  \
    float a_ = *(const float*)(AlsB + (__float_as_uint(QV) & 255u));        \
    float s_ = fminf(fmaf(a_, (BV), 0.5f), 4095.0f);                        \
    ACCJ = fmaf((QV), Tls[(unsigned)s_], ACCJ); }

  float acc[8];
#pragma unroll
  for (int jj = 0; jj < 8; ++jj) acc[jj] = 0.f;

#pragma unroll
  for (int jj = 0; jj < 8; ++jj) {
    int jl = g * 8 + jj;  // uniform
    int n = (int)__builtin_amdgcn_readfirstlane(Cnt[bh * 256 + jblk * 32 + jl]);
    const float4* P4 = reinterpret_cast<const float4*>(Cb + (bh * 256 + jblk * 32 + jl) * 64);
    float a0 = 0.f, a1 = 0.f;
#pragma unroll 1
    for (int s = 0; s < n; s += 4) {
      float4 u = P4[s >> 1];        // (b0,q0,b1,q1) — wave-uniform -> s_load
      float4 v = P4[(s >> 1) + 1];  // (b2,q2,b3,q3)
      EV(u.x, u.y, a0);
      EV(u.z, u.w, a1);
      EV(v.x, v.y, a0);
      EV(v.z, v.w, a1);
    }
    acc[jj] = a0 + a1;
  }
#undef EV

  float rs = 0.f;
#pragma unroll
  for (int jj = 0; jj < 8; ++jj) rs += acc[jj];
  red[t] = rs;

  int lane = t & 63, w = t >> 6;
#pragma unroll
  for (int jj = 0; jj < 8; ++jj) {
    float v = acc[jj];
#pragma unroll
    for (int off = 32; off >= 1; off >>= 1) v += __shfl_xor(v, off);
    if (lane == 0) cpart[w][jj] = v;
  }
  __syncthreads();
  if (t < 128) {
    rowpart[(bh * 8 + jblk) * 256 + isplit * 128 + t] =
        red[t] + red[t + 128] + red[t + 256] + red[t + 384];
  } else if (t < 160) {
    int jl = t - 128;
    int gg = jl >> 3, jj = jl & 7;
    colsum[(bh * 2 + isplit) * 256 + jblk * 32 + jl] =
        cpart[2 * gg][jj] + cpart[2 * gg + 1][jj];
  }
}

// ---------------------------------------------------------------------------
// Stage 3: per (bh): softmax over 256 row/col means, temps to ws, pooled
// outputs into out[0:8192].  512 threads.
// ---------------------------------------------------------------------------
__global__ __launch_bounds__(512) void softmax_pool_kernel(
    const float* __restrict__ rowpart, const float* __restrict__ colsum,
    const float* __restrict__ A0, const float* __restrict__ B0,
    float* __restrict__ b2a, float* __restrict__ a2b, float* __restrict__ out) {
  int bh = blockIdx.x;
  int b = bh >> 3, h = bh & 7;
  int t = threadIdx.x;
  int tt = t & 255;
  int lane = t & 63, w = (t >> 6) & 3;
  __shared__ float redA[4], redB[4], redC[4], redD[4];
  __shared__ float tA[256], tB[256];
  __shared__ float pp[8][64];

  float r = 0.f;
#pragma unroll
  for (int jb = 0; jb < 8; ++jb) r += rowpart[(bh * 8 + jb) * 256 + tt];
  r *= (1.f / 256.f);
  float cs = (colsum[(bh * 2 + 0) * 256 + tt] + colsum[(bh * 2 + 1) * 256 + tt]) * (1.f / 256.f);

  float mr = r, mc = cs;
#pragma unroll
  for (int off = 32; off >= 1; off >>= 1) {
    mr = fmaxf(mr, __shfl_xor(mr, off));
    mc = fmaxf(mc, __shfl_xor(mc, off));
  }
  if (lane == 0) { redA[w] = mr; redB[w] = mc; }
  __syncthreads();
  mr = fmaxf(fmaxf(redA[0], redA[1]), fmaxf(redA[2], redA[3]));
  mc = fmaxf(fmaxf(redB[0], redB[1]), fmaxf(redB[2], redB[3]));

  float er = fast_exp2((r - mr) * LOG2E);
  float ec = fast_exp2((cs - mc) * LOG2E);
  float sr = er, sc = ec;
#pragma unroll
  for (int off = 32; off >= 1; off >>= 1) {
    sr += __shfl_xor(sr, off);
    sc += __shfl_xor(sc, off);
  }
  if (lane == 0) { redC[w] = sr; redD[w] = sc; }
  __syncthreads();
  sr = redC[0] + redC[1] + redC[2] + redC[3];
  sc = redD[0] + redD[1] + redD[2] + redD[3];

  float vb2a = er * fast_rcp(sr);
  float va2b = ec * fast_rcp(sc);
  tA[tt] = vb2a; tB[tt] = va2b;
  b2a[bh * 256 + tt] = vb2a;
  a2b[bh * 256 + tt] = va2b;
  __syncthreads();

  int c = t & 63, iq = t >> 6;  // 8 groups x 32 i
  const float* Ab = A0 + b * 131072 + h * 16384;
  const float* Bb = B0 + b * 131072 + h * 16384;
  float pa = 0.f, pb = 0.f;
#pragma unroll 4
  for (int ii = 0; ii < 32; ++ii) {
    int i = (iq << 5) + ii;
    pa = fmaf(Ab[i * 64 + c], tA[i], pa);
    pb = fmaf(Bb[i * 64 + c], tB[i], pb);
  }
  pp[iq][c] = pa;
  __syncthreads();
  if (t < 64) {
    float s = 0.f;
#pragma unroll
    for (int k = 0; k < 8; ++k) s += pp[k][t];
    out[b * 1024 + h * 64 + t] = s;
  }
  __syncthreads();
  pp[iq][c] = pb;
  __syncthreads();
  if (t < 64) {
    float s = 0.f;
#pragma unroll
    for (int k = 0; k < 8; ++k) s += pp[k][t];
    out[b * 1024 + 512 + h * 64 + t] = s;
  }
}

// ---------------------------------------------------------------------------
// Stage 4: out1[b,i] = mean_h temp_b2a ; out2[b,j] = mean_h temp_a2b
// ---------------------------------------------------------------------------
__global__ __launch_bounds__(256) void mean_heads_kernel(
    const float* __restrict__ b2a, const float* __restrict__ a2b,
    float* __restrict__ out) {
  int b = blockIdx.x, t = threadIdx.x;
  float s1 = 0.f, s2 = 0.f;
#pragma unroll
  for (int h = 0; h < 8; ++h) {
    s1 += b2a[(b * 8 + h) * 256 + t];
    s2 += a2b[(b * 8 + h) * 256 + t];
  }
  out[8192 + b * 256 + t] = s1 * 0.125f;
  out[10240 + b * 256 + t] = s2 * 0.125f;
}

extern "C" void kernel_launch(void* const* d_in, const int* in_sizes, int n_in,
                              void* d_out, int out_size, void* d_ws, size_t ws_size,
                              hipStream_t stream) {
  const float* A  = (const float*)d_in[0];
  const float* B  = (const float*)d_in[1];
  const float* W1 = (const float*)d_in[2];
  const float* b1 = (const float*)d_in[3];
  const float* W2 = (const float*)d_in[4];
  const float* b2 = (const float*)d_in[5];
  const float* q  = (const float*)d_in[6];
  float* out = (float*)d_out;
  float* ws = (float*)d_ws;

  float*    Ar      = ws;                          // 1,048,576 f
  float*    Brr     = ws + 1048576;                // 1,048,576 f
  float2*   Cb      = (float2*)(ws + 2097152);     // 1,048,576 f2 (8 MB)
  unsigned* Cnt     = (unsigned*)(ws + 4194304);   // 16,384 u32
  float*    rowpart = ws + 4227072;                // 131,072 f
  float*    colsum  = ws + 4358144;                // 32,768 f  (end ~17.6 MB)
  float*    b2a     = ws;                          // alias Ar (dead after attmap)
  float*    a2b     = ws + 16384;

  gemm_mfma_kernel<<<dim3(16, 8, 2), 256, 0, stream>>>(A, W1, b1, Ar, B, W2, b2, Brr);
  compact_kernel<<<512, 256, 0, stream>>>(Brr, q, Cb, Cnt);
  attmap_kernel<<<dim3(64, 8, 2), 512, 0, stream>>>(Ar, Cb, Cnt, rowpart, colsum);
  softmax_pool_kernel<<<64, 512, 0, stream>>>(rowpart, colsum, A, B, b2a, a2b, out);
  mean_heads_kernel<<<8, 256, 0, stream>>>(b2a, a2b, out);
}